// Round 16
// baseline (45.395 us; speedup 1.0000x reference)
//
#include <hip/hip_runtime.h>
#include <hip/hip_bf16.h>

typedef float f32x4 __attribute__((ext_vector_type(4)));
typedef short bf16x8 __attribute__((ext_vector_type(8)));

__device__ inline unsigned cvt_pk_bf16(float a, float b) {
    unsigned r;
    asm("v_cvt_pk_bf16_f32 %0, %1, %2" : "=v"(r) : "v"(a), "v"(b));
    return r;
}
union FragU { unsigned u[4]; bf16x8 v; };

__device__ inline bf16x8 pack8(const float* f) {
    FragU x;
    x.u[0] = cvt_pk_bf16(f[0], f[1]);
    x.u[1] = cvt_pk_bf16(f[2], f[3]);
    x.u[2] = cvt_pk_bf16(f[4], f[5]);
    x.u[3] = cvt_pk_bf16(f[6], f[7]);
    return x.v;
}

// exact fp32 -> bf16 hi+lo split of 8 values
__device__ inline void split_hl(const float* v, bf16x8& h8, bf16x8& l8) {
    float hi[8], lo[8];
    #pragma unroll
    for (int e = 0; e < 8; ++e) {
        float h = __bfloat162float(__float2bfloat16(v[e]));
        hi[e] = h; lo[e] = v[e] - h;
    }
    h8 = pack8(hi); l8 = pack8(lo);
}

__device__ inline float swz16_f(float v) {   // lane ^= 16 within each 32-lane half
    return __int_as_float(__builtin_amdgcn_ds_swizzle(__float_as_int(v), 0x401F));
}

#define POWERS(p, xx)                                              \
    p[0] = 1.f;  p[1] = (xx);      p[2] = p[1]*p[1];               \
    p[3] = p[2]*p[1]; p[4] = p[2]*p[2]; p[5] = p[4]*p[1];          \
    p[6] = p[4]*p[2]; p[7] = p[4]*p[3];

#define MFMA __builtin_amdgcn_mfma_f32_16x16x32_bf16

__global__ __launch_bounds__(256, 4) void tt_poly_kernel(
    const float* __restrict__ X,
    const float* __restrict__ G0,   // [d1][r]
    const float* __restrict__ G1,   // [r][d1][s]
    const float* __restrict__ G2,   // [s][d1][t]
    const float* __restrict__ G3,   // [t][d1]
    float* __restrict__ out,
    int B, int NW)
{
    const int tid   = threadIdx.x;
    const int lane  = tid & 63;
    const int row16 = lane & 15;    // C col: sample-within-group; also A row
    const int quad  = lane >> 4;
    const int s8    = row16 & 7;    // output index this lane's A-row produces (mirrored)
    const int gw    = blockIdx.x * 4 + (tid >> 6);

    // ---- per-wave constant A-fragments (G on A side; rows mirrored via s8) ----
    bf16x8 A1h[2], A1l[2], A2h[2], A2l[2], A3h[2], A3l[2];
    #pragma unroll
    for (int q = 0; q < 2; ++q) {
        float v[8];
        #pragma unroll
        for (int e = 0; e < 8; ++e) {
            float a = 0.f;
            #pragma unroll
            for (int r = 0; r < 8; ++r)
                a = fmaf(G0[e*8 + r], G1[(r*8 + 4*q + quad)*8 + s8], a);
            v[e] = a;
        }
        split_hl(v, A1h[q], A1l[q]);
    }
    #pragma unroll
    for (int q = 0; q < 2; ++q) {
        float v[8];
        #pragma unroll
        for (int e = 0; e < 8; ++e)
            v[e] = G2[(e*8 + 4*q + quad)*8 + s8];
        split_hl(v, A2h[q], A2l[q]);
    }
    #pragma unroll
    for (int q = 0; q < 2; ++q) {
        float v[8];
        #pragma unroll
        for (int e = 0; e < 8; ++e)
            v[e] = G3[e*8 + 4*q + quad];
        split_hl(v, A3h[q], A3l[q]);
    }

    const bool oddq = (quad & 1) != 0;

    #pragma unroll 1
    for (int it = 0; it < 4; ++it) {
        const int sbase = (it * NW + gw) * 64;
        float resg[4];

        #pragma unroll
        for (int g4 = 0; g4 < 4; ++g4) {
            // transposed X load: all quads fetch the group's 16 samples (L1 broadcast)
            const int sidx = sbase + g4 * 16 + row16;
            float4 xs = (sidx < B) ? reinterpret_cast<const float4*>(X)[sidx]
                                   : make_float4(0.f, 0.f, 0.f, 0.f);

            // ---- S2: B_q slot e = x0^e * x1^(4q+quad) ----
            float p0[8];
            POWERS(p0, xs.x)
            float x1sq = xs.y * xs.y, x1q4 = x1sq * x1sq;
            float sA = ((quad & 1) ? xs.y : 1.f) * ((quad & 2) ? x1sq : 1.f);
            float sB = sA * x1q4;
            float f0[8], f1[8];
            #pragma unroll
            for (int e = 0; e < 8; ++e) { f0[e] = p0[e] * sA; f1[e] = p0[e] * sB; }
            bf16x8 b0 = pack8(f0), b1 = pack8(f1);
            f32x4 ah = {0.f, 0.f, 0.f, 0.f}, al = {0.f, 0.f, 0.f, 0.f};
            ah = MFMA(A1h[0], b0, ah, 0, 0, 0);
            al = MFMA(A1l[0], b0, al, 0, 0, 0);
            ah = MFMA(A1h[1], b1, ah, 0, 0, 0);
            al = MFMA(A1l[1], b1, al, 0, 0, 0);
            f32x4 acc = ah + al;

            // gather t1[0..7][row16]: own quad has one parity half, partner the other
            float t1v[8];
            {
                float sw0 = swz16_f(acc[0]), sw1 = swz16_f(acc[1]);
                float sw2 = swz16_f(acc[2]), sw3 = swz16_f(acc[3]);
                t1v[0] = oddq ? sw0 : acc[0];  t1v[4] = oddq ? acc[0] : sw0;
                t1v[1] = oddq ? sw1 : acc[1];  t1v[5] = oddq ? acc[1] : sw1;
                t1v[2] = oddq ? sw2 : acc[2];  t1v[6] = oddq ? acc[2] : sw2;
                t1v[3] = oddq ? sw3 : acc[3];  t1v[7] = oddq ? acc[3] : sw3;
            }

            // ---- S3: B_q slot e = t1[e] * x2^(4q+quad) ----
            float x2sq = xs.z * xs.z, x2q4 = x2sq * x2sq;
            float uA = ((quad & 1) ? xs.z : 1.f) * ((quad & 2) ? x2sq : 1.f);
            float uB = uA * x2q4;
            #pragma unroll
            for (int e = 0; e < 8; ++e) { f0[e] = t1v[e] * uA; f1[e] = t1v[e] * uB; }
            b0 = pack8(f0); b1 = pack8(f1);
            f32x4 bh = {0.f, 0.f, 0.f, 0.f}, bl = {0.f, 0.f, 0.f, 0.f};
            bh = MFMA(A2h[0], b0, bh, 0, 0, 0);
            bl = MFMA(A2l[0], b0, bl, 0, 0, 0);
            bh = MFMA(A2h[1], b1, bh, 0, 0, 0);
            bl = MFMA(A2l[1], b1, bl, 0, 0, 0);
            f32x4 acc2 = bh + bl;

            // gather t2[0..7][row16]
            float t2v[8];
            {
                float sw0 = swz16_f(acc2[0]), sw1 = swz16_f(acc2[1]);
                float sw2 = swz16_f(acc2[2]), sw3 = swz16_f(acc2[3]);
                t2v[0] = oddq ? sw0 : acc2[0];  t2v[4] = oddq ? acc2[0] : sw0;
                t2v[1] = oddq ? sw1 : acc2[1];  t2v[5] = oddq ? acc2[1] : sw1;
                t2v[2] = oddq ? sw2 : acc2[2];  t2v[6] = oddq ? acc2[2] : sw2;
                t2v[3] = oddq ? sw3 : acc2[3];  t2v[7] = oddq ? acc2[3] : sw3;
            }

            // ---- S4: B_q slot e = t2[e] * x3^(4q+quad); all C rows = res ----
            float x3sq = xs.w * xs.w, x3q4 = x3sq * x3sq;
            float wA = ((quad & 1) ? xs.w : 1.f) * ((quad & 2) ? x3sq : 1.f);
            float wB = wA * x3q4;
            #pragma unroll
            for (int e = 0; e < 8; ++e) { f0[e] = t2v[e] * wA; f1[e] = t2v[e] * wB; }
            b0 = pack8(f0); b1 = pack8(f1);
            f32x4 ch = {0.f, 0.f, 0.f, 0.f}, cl = {0.f, 0.f, 0.f, 0.f};
            ch = MFMA(A3h[0], b0, ch, 0, 0, 0);
            cl = MFMA(A3l[0], b0, cl, 0, 0, 0);
            ch = MFMA(A3h[1], b1, ch, 0, 0, 0);
            cl = MFMA(A3l[1], b1, cl, 0, 0, 0);
            resg[g4] = ch[0] + cl[0];
        }

        // lane l stores sample sbase + l  (group = quad, col = row16)
        float rv = (quad & 2) ? ((quad & 1) ? resg[3] : resg[2])
                              : ((quad & 1) ? resg[1] : resg[0]);
        const int b = sbase + lane;
        if (b < B) out[b] = rv;
    }
}

extern "C" void kernel_launch(void* const* d_in, const int* in_sizes, int n_in,
                              void* d_out, int out_size, void* d_ws, size_t ws_size,
                              hipStream_t stream) {
    const float* X  = (const float*)d_in[0];
    const float* G0 = (const float*)d_in[1];
    const float* G1 = (const float*)d_in[2];
    const float* G2 = (const float*)d_in[3];
    const float* G3 = (const float*)d_in[4];
    float* out = (float*)d_out;

    int B = in_sizes[0] / 4;                       // X is [B,4]
    int block = 256;
    int grid = (B + 1023) / 1024;                  // 1024 samples per block
    int NW = grid * 4;                             // total waves
    tt_poly_kernel<<<grid, block, 0, stream>>>(X, G0, G1, G2, G3, out, B, NW);
}

// Round 18
// 40.439 us; speedup vs baseline: 1.1226x; 1.1226x over previous
//
#include <hip/hip_runtime.h>
#include <hip/hip_bf16.h>

typedef float f32x4 __attribute__((ext_vector_type(4)));
typedef float v2f  __attribute__((ext_vector_type(2)));
typedef short bf16x8 __attribute__((ext_vector_type(8)));

__device__ inline unsigned cvt_pk_bf16(float a, float b) {
    unsigned r;
    asm("v_cvt_pk_bf16_f32 %0, %1, %2" : "=v"(r) : "v"(a), "v"(b));
    return r;
}
union FragU { unsigned u[4]; bf16x8 v; };

__device__ inline bf16x8 pack8(const float* f) {
    FragU x;
    x.u[0] = cvt_pk_bf16(f[0], f[1]);
    x.u[1] = cvt_pk_bf16(f[2], f[3]);
    x.u[2] = cvt_pk_bf16(f[4], f[5]);
    x.u[3] = cvt_pk_bf16(f[6], f[7]);
    return x.v;
}
// pack 4 v2f pairs
__device__ inline bf16x8 pack8p(const v2f* f) {
    FragU x;
    x.u[0] = cvt_pk_bf16(f[0].x, f[0].y);
    x.u[1] = cvt_pk_bf16(f[1].x, f[1].y);
    x.u[2] = cvt_pk_bf16(f[2].x, f[2].y);
    x.u[3] = cvt_pk_bf16(f[3].x, f[3].y);
    return x.v;
}

// exact fp32 -> bf16 hi+lo split
__device__ inline void split_hl(const float* v, bf16x8& h8, bf16x8& l8) {
    float hi[8], lo[8];
    #pragma unroll
    for (int e = 0; e < 8; ++e) {
        float h = __bfloat162float(__float2bfloat16(v[e]));
        hi[e] = h; lo[e] = v[e] - h;
    }
    h8 = pack8(hi); l8 = pack8(lo);
}

__device__ inline float bperm_f(int idx_bytes, float v) {
    return __int_as_float(__builtin_amdgcn_ds_bpermute(idx_bytes, __float_as_int(v)));
}
__device__ inline float swz16_f(float v) {   // lane ^= 16
    return __int_as_float(__builtin_amdgcn_ds_swizzle(__float_as_int(v), 0x401F));
}

#define POWERS(p, xx)                                              \
    p[0] = 1.f;  p[1] = (xx);      p[2] = p[1]*p[1];               \
    p[3] = p[2]*p[1]; p[4] = p[2]*p[2]; p[5] = p[4]*p[1];          \
    p[6] = p[4]*p[2]; p[7] = p[4]*p[3];

#define MFMA __builtin_amdgcn_mfma_f32_16x16x32_bf16
#define IT 2

__global__ __launch_bounds__(256, 2) void tt_poly_kernel(
    const float* __restrict__ X,
    const float* __restrict__ G0,   // [d1][r]
    const float* __restrict__ G1,   // [r][d1][s]
    const float* __restrict__ G2,   // [s][d1][t]
    const float* __restrict__ G3,   // [t][d1]
    float* __restrict__ out,
    int B, int NW)
{
    const int tid   = threadIdx.x;
    const int lane  = tid & 63;
    const int row16 = lane & 15;
    const int quad  = lane >> 4;
    const int s8    = row16 & 7;         // mirrored A-row output index
    const int p     = quad & 1;          // parity: odd quads see rotated gathers
    const int gw    = blockIdx.x * 4 + (tid >> 6);

    // ---- prefetch X for IT iterations ----
    float4 xva[IT];
    #pragma unroll
    for (int it = 0; it < IT; ++it) {
        int b = (it * NW + gw) * 64 + lane;
        xva[it] = (b < B) ? reinterpret_cast<const float4*>(X)[b]
                          : make_float4(0.f, 0.f, 0.f, 0.f);
    }

    // ---- per-wave constant A-fragments ----
    // S2: A1 slot(q,e) = H1[e][4q+quad][s8], H1 = G0.G1 exact fp32
    bf16x8 A1h[2], A1l[2], A2h[2], A2l[2], A3h[2];
    #pragma unroll
    for (int q = 0; q < 2; ++q) {
        float v[8];
        #pragma unroll
        for (int e = 0; e < 8; ++e) {
            float a = 0.f;
            #pragma unroll
            for (int r = 0; r < 8; ++r)
                a = fmaf(G0[e*8 + r], G1[(r*8 + 4*q + quad)*8 + s8], a);
            v[e] = a;
        }
        split_hl(v, A1h[q], A1l[q]);
    }
    // S3: A2 slot(q,e) = G2[s=perm(e)][4q+quad][s8]; perm folds odd-quad rotation
    #pragma unroll
    for (int q = 0; q < 2; ++q) {
        float v[8];
        #pragma unroll
        for (int e = 0; e < 8; ++e) {
            int su = p ? ((e + 4) & 7) : e;
            v[e] = G2[(su*8 + 4*q + quad)*8 + s8];
        }
        split_hl(v, A2h[q], A2l[q]);
    }
    // S4: A3 slot(q,e) = G3[t=perm(e)][4q+quad]; row-independent, hi-only
    #pragma unroll
    for (int q = 0; q < 2; ++q) {
        float v[8];
        #pragma unroll
        for (int e = 0; e < 8; ++e) {
            int tu = p ? ((e + 4) & 7) : e;
            v[e] = G3[tu*8 + 4*q + quad];
        }
        bf16x8 l8;
        split_hl(v, A3h[q], l8);
    }

    #pragma unroll
    for (int it = 0; it < IT; ++it) {
        const int sbase = (it * NW + gw) * 64;
        const float4 xv = xva[it];

        // ---- hoisted broadcasts: all groups' x components (off the MFMA chain) ----
        float x0g[4], x1g[4], x2g[4], x3g[4];
        #pragma unroll
        for (int g = 0; g < 4; ++g) {
            const int src = (g * 16 + row16) * 4;
            x0g[g] = bperm_f(src, xv.x);
            x1g[g] = bperm_f(src, xv.y);
            x2g[g] = bperm_f(src, xv.z);
            x3g[g] = bperm_f(src, xv.w);
        }

        float resg[4];

        #pragma unroll
        for (int g4 = 0; g4 < 4; ++g4) {
            // ---- S2: B slot e = x0^e * x1^(4q+quad) ----
            float p0[8];
            POWERS(p0, x0g[g4])
            float x1v = x1g[g4];
            float x1sq = x1v * x1v, x1q4 = x1sq * x1sq;
            float sA = (p ? x1v : 1.f) * ((quad & 2) ? x1sq : 1.f);
            float sB = sA * x1q4;
            v2f pr[4] = {{p0[0],p0[1]},{p0[2],p0[3]},{p0[4],p0[5]},{p0[6],p0[7]}};
            v2f f0[4], f1[4];
            v2f vA = {sA, sA}, vB = {sB, sB};
            #pragma unroll
            for (int j = 0; j < 4; ++j) { f0[j] = pr[j] * vA; f1[j] = pr[j] * vB; }
            bf16x8 b0 = pack8p(f0), b1 = pack8p(f1);
            f32x4 zh = {0.f,0.f,0.f,0.f};
            f32x4 ah = MFMA(A1h[0], b0, zh, 0, 0, 0);
            f32x4 al = MFMA(A1l[0], b0, zh, 0, 0, 0);
            ah = MFMA(A1h[1], b1, ah, 0, 0, 0);
            al = MFMA(A1l[1], b1, al, 0, 0, 0);
            f32x4 acc = ah + al;

            // gather into fixed register order [own0..3, partner0..3];
            // the parity rotation is folded into A2/A3's slot permutation
            v2f t1p[4];
            {
                float sw0 = swz16_f(acc[0]), sw1 = swz16_f(acc[1]);
                float sw2 = swz16_f(acc[2]), sw3 = swz16_f(acc[3]);
                t1p[0] = (v2f){acc[0], acc[1]};
                t1p[1] = (v2f){acc[2], acc[3]};
                t1p[2] = (v2f){sw0, sw1};
                t1p[3] = (v2f){sw2, sw3};
            }

            // ---- S3: B slot e = t1perm[e] * x2^(4q+quad) ----
            float x2v = x2g[g4];
            float x2sq = x2v * x2v, x2q4 = x2sq * x2sq;
            float uA = (p ? x2v : 1.f) * ((quad & 2) ? x2sq : 1.f);
            float uB = uA * x2q4;
            v2f vU = {uA, uA}, vV = {uB, uB};
            #pragma unroll
            for (int j = 0; j < 4; ++j) { f0[j] = t1p[j] * vU; f1[j] = t1p[j] * vV; }
            b0 = pack8p(f0); b1 = pack8p(f1);
            f32x4 bh = MFMA(A2h[0], b0, zh, 0, 0, 0);
            f32x4 bl = MFMA(A2l[0], b0, zh, 0, 0, 0);
            bh = MFMA(A2h[1], b1, bh, 0, 0, 0);
            bl = MFMA(A2l[1], b1, bl, 0, 0, 0);
            f32x4 acc2 = bh + bl;

            v2f t2p[4];
            {
                float sw0 = swz16_f(acc2[0]), sw1 = swz16_f(acc2[1]);
                float sw2 = swz16_f(acc2[2]), sw3 = swz16_f(acc2[3]);
                t2p[0] = (v2f){acc2[0], acc2[1]};
                t2p[1] = (v2f){acc2[2], acc2[3]};
                t2p[2] = (v2f){sw0, sw1};
                t2p[3] = (v2f){sw2, sw3};
            }

            // ---- S4: B slot e = t2perm[e] * x3^(4q+quad); all C rows = res ----
            float x3v = x3g[g4];
            float x3sq = x3v * x3v, x3q4 = x3sq * x3sq;
            float wA = (p ? x3v : 1.f) * ((quad & 2) ? x3sq : 1.f);
            float wB = wA * x3q4;
            v2f vW = {wA, wA}, vZ = {wB, wB};
            #pragma unroll
            for (int j = 0; j < 4; ++j) { f0[j] = t2p[j] * vW; f1[j] = t2p[j] * vZ; }
            b0 = pack8p(f0); b1 = pack8p(f1);
            f32x4 acc3 = MFMA(A3h[0], b0, zh, 0, 0, 0);
            acc3 = MFMA(A3h[1], b1, acc3, 0, 0, 0);
            resg[g4] = acc3[0];
        }

        float rv = (quad & 2) ? ((quad & 1) ? resg[3] : resg[2])
                              : ((quad & 1) ? resg[1] : resg[0]);
        const int b = sbase + lane;
        if (b < B) out[b] = rv;
    }
}

extern "C" void kernel_launch(void* const* d_in, const int* in_sizes, int n_in,
                              void* d_out, int out_size, void* d_ws, size_t ws_size,
                              hipStream_t stream) {
    const float* X  = (const float*)d_in[0];
    const float* G0 = (const float*)d_in[1];
    const float* G1 = (const float*)d_in[2];
    const float* G2 = (const float*)d_in[3];
    const float* G3 = (const float*)d_in[4];
    float* out = (float*)d_out;

    int B = in_sizes[0] / 4;                            // X is [B,4]
    int block = 256;
    int grid = (B + 64 * 4 * IT - 1) / (64 * 4 * IT);   // 512 samples per block
    int NW = grid * 4;                                  // total waves
    tt_poly_kernel<<<grid, block, 0, stream>>>(X, G0, G1, G2, G3, out, B, NW);
}